// Round 11
// baseline (366.339 us; speedup 1.0000x reference)
//
#include <hip/hip_runtime.h>
#include <hip/hip_bf16.h>
#include <math.h>

// Problem constants
#define B_  16
#define LP_ 512
#define LA_ 32
#define DP_ 1024
#define DA_ 512
#define HH_ 512
#define DO_ 1024

typedef unsigned short ushort_t;
typedef __attribute__((ext_vector_type(8))) short bf16x8;
typedef __attribute__((ext_vector_type(4))) float f32x4;

__device__ __forceinline__ ushort_t f2bs(float x) {
    __hip_bfloat16 b = __float2bfloat16(x);
    return *(ushort_t*)&b;
}
__device__ __forceinline__ float bs2f(ushort_t u) {
    __hip_bfloat16 b = *(__hip_bfloat16*)&u;
    return __bfloat162float(b);
}

// Async global->LDS copy, 16B per lane, wave-uniform LDS base.
__device__ __forceinline__ void gload16(const ushort_t* g, ushort_t* l) {
    __builtin_amdgcn_global_load_lds(
        (const __attribute__((address_space(1))) void*)g,
        (__attribute__((address_space(3))) void*)l, 16, 0, 0);
}

// LESSONS ENCODED (measured):
//  r8:  no XCD swizzle — with nbx==8 the natural bid%8 round-robin already maps
//       one B-panel per XCD L2; contiguous-chunk swizzle thrashed L2 (112->146us).
//  r9:  no trunc-hi bit-twiddle staging — RNE/RNE f2bs staging runs 112-113us
//       @ VGPR=96; trunc variant ran 146-155us @ VGPR=84. Keep RNE (r10 confirm).
//  r10: 354us total; final GEMM 113us (MfmaUtil 29, VALU 30, ~40% barrier/stage
//       stall). This round: B-staging via global_load_lds (B LDS linear).

// ---------------- dtype detector ----------------
// f32 storage -> low mantissa halves viewed as bf16 have huge random exponents.
// 10 passing rounds: flag==1 (f32). If flag==0 nothing runs -> loud fail.
__global__ void detect_mode(const unsigned short* __restrict__ raw,
                            int* __restrict__ flag) {
    __shared__ int cnt;
    if (threadIdx.x == 0) cnt = 0;
    __syncthreads();
    int e = (raw[threadIdx.x] >> 7) & 0xFF;
    if (e >= 160) atomicAdd(&cnt, 1);
    __syncthreads();
    if (threadIdx.x == 0) *flag = (cnt > 0) ? 1 : 0;
}

// ---------------- fused transpose-split for all 3 weights (1 launch) --------
// f32 src[R][C] -> bf16 hi/lo planes dst[C][R] (RNE hi + RNE residual lo).
// grid sections: Wa 256 | Wp 512 | Wo 1536   (total 2304 blocks)
__global__ __launch_bounds__(256) void transpose_split_all(
    const int* __restrict__ flag,
    const float* __restrict__ Wa, ushort_t* __restrict__ WaTH, ushort_t* __restrict__ WaTL,
    const float* __restrict__ Wp, ushort_t* __restrict__ WpTH, ushort_t* __restrict__ WpTL,
    const float* __restrict__ Wo, ushort_t* __restrict__ WoTH, ushort_t* __restrict__ WoTL)
{
    if (*flag != 1) return;
    __shared__ float tile[32][33];
    int bid = blockIdx.x;
    const float* src; ushort_t* dH; ushort_t* dL; int R, C;
    if (bid < 256)      { src = Wa; dH = WaTH; dL = WaTL; R = DA_;       C = HH_; }
    else if (bid < 768) { src = Wp; dH = WpTH; dL = WpTL; R = DP_;       C = HH_; bid -= 256; }
    else                { src = Wo; dH = WoTH; dL = WoTL; R = DP_ + DA_; C = DO_; bid -= 768; }
    const int nbx = C / 32;
    const int bx = bid % nbx;
    const int by = bid / nbx;
    const int tx = threadIdx.x % 32, ty = threadIdx.x / 32;  // 32x8
    const int c0 = bx * 32, r0 = by * 32;
#pragma unroll
    for (int i = ty; i < 32; i += 8)
        tile[i][tx] = src[(size_t)(r0 + i) * C + c0 + tx];
    __syncthreads();
#pragma unroll
    for (int i = ty; i < 32; i += 8) {
        float x = tile[tx][i];
        ushort_t h = f2bs(x);
        float lo = x - bs2f(h);
        dH[(size_t)(c0 + i) * R + r0 + tx] = h;
        dL[(size_t)(c0 + i) * R + r0 + tx] = f2bs(lo);
    }
}

// ---------------- Split-bf16 MFMA GEMM ----------------
// C_f32[M,N] = A_f32[M,K] @ B[K,N] + bias; B as transposed bf16 hi/lo planes
// BTH/BTL [N][K]. 3 MFMA per fragment pair: AhBh + AhBl + AlBh (AlBl dropped,
// ~2^-16 rel). A split in-staging via RNE f2bs pairs (compiler fuses to
// v_cvt_pk_bf16_f32); A LDS padded (SA=40). B staged via global_load_lds
// width=16 into LINEAR LDS (SB=32 — gload_lds requires contiguous dest, m173;
// resulting 8-way b128 read conflict is hidden at 2-phase, m252).
// A/B fragments share the same (lane-group,slot)->k convention -> any HW
// k-permutation cancels. C/D: col=lane&15, row=(lane>>4)*4+reg [m89].
template<int BMt, int BNt, int CONCAT, int RELU>
__global__ __launch_bounds__(256) void gemm_mfma_split(
    const int* __restrict__ flag,
    const float* __restrict__ A0,
    const float* __restrict__ A1,
    const ushort_t* __restrict__ BTH,
    const ushort_t* __restrict__ BTL,
    const float* __restrict__ bias,
    float* __restrict__ Cout,
    int N, int K)
{
    if (*flag != 1) return;
    constexpr int SA = 40;   // A: 80B row stride, 16B-aligned b128, banks spread
    constexpr int SB = 32;   // B: linear rows (global_load_lds destination)
    __shared__ ushort_t AsH[BMt * SA];
    __shared__ ushort_t AsL[BMt * SA];
    __shared__ ushort_t BsH[BNt * SB];
    __shared__ ushort_t BsL[BNt * SB];
    const int tid = threadIdx.x;
    const int nbx = N / BNt;
    const int colBase = (blockIdx.x % nbx) * BNt;
    const int rowBase = (blockIdx.x / nbx) * BMt;
    const int wid = tid >> 6, lane = tid & 63;
    const int wr = wid >> 1, wc = wid & 1;          // 2x2 wave grid
    const int lrow = lane & 15;
    const int lk8 = (lane >> 4) * 8;
    constexpr int FM = (BMt / 2) / 16;
    constexpr int FN = (BNt / 2) / 16;

    f32x4 acc[FM][FN] = {};

    for (int k0 = 0; k0 < K; k0 += 32) {
        // ---- stage A [BMt][32] f32 -> split hi/lo LDS (RNE/RNE, r3 form) ----
#pragma unroll
        for (int c = 0; c < BMt / 32; c++) {
            const int s = tid + c * 256;       // BMt*8 float4 slots
            const int row = s >> 3, k4 = (s & 7) * 4;
            const int gk = k0 + k4;            // mult of 4; never straddles DP_
            const float* ap;
            if (CONCAT) {
                ap = (gk < DP_) ? A0 + (size_t)(rowBase + row) * DP_ + gk
                                : A1 + (size_t)(rowBase + row) * DA_ + (gk - DP_);
            } else {
                ap = A0 + (size_t)(rowBase + row) * K + gk;
            }
            const float4 v = *(const float4*)ap;
            const float xs[4] = {v.x, v.y, v.z, v.w};
            ushort_t h[4], l[4];
#pragma unroll
            for (int j = 0; j < 4; j++) {
                h[j] = f2bs(xs[j]);
                l[j] = f2bs(xs[j] - bs2f(h[j]));
            }
            *(uint2*)&AsH[row * SA + k4] = *(const uint2*)h;
            *(uint2*)&AsL[row * SA + k4] = *(const uint2*)l;
        }
        // ---- stage B [BNt][32] via async global_load_lds (1KB chunk/wave) ----
        // chunk c = rows [c*16,(c+1)*16): lane covers row c*16+(lane>>2),
        // k8=(lane&3)*8 -> LDS byte = chunk_base + lane*16 (linear). Global src
        // is per-lane; LDS base wave-uniform. __syncthreads drains vmcnt.
        {
            const int crow = lane >> 2;          // 0..15
            const int ck8  = (lane & 3) * 8;     // 0,8,16,24
            for (int c = wid; c < BNt / 16; c += 4) {
                const size_t goff =
                    (size_t)(colBase + c * 16 + crow) * K + k0 + ck8;
                gload16(BTH + goff, &BsH[c * 512]);
                gload16(BTL + goff, &BsL[c * 512]);
            }
        }
        __syncthreads();

        bf16x8 ah[FM], al[FM], bh[FN], bl[FN];
#pragma unroll
        for (int m = 0; m < FM; m++) {
            const int r = (wr * (BMt / 2) + m * 16 + lrow) * SA + lk8;
            ah[m] = *(const bf16x8*)&AsH[r];
            al[m] = *(const bf16x8*)&AsL[r];
        }
#pragma unroll
        for (int n = 0; n < FN; n++) {
            const int r = (wc * (BNt / 2) + n * 16 + lrow) * SB + lk8;
            bh[n] = *(const bf16x8*)&BsH[r];
            bl[n] = *(const bf16x8*)&BsL[r];
        }
#pragma unroll
        for (int m = 0; m < FM; m++)
#pragma unroll
            for (int n = 0; n < FN; n++) {
                acc[m][n] = __builtin_amdgcn_mfma_f32_16x16x32_bf16(
                    ah[m], bh[n], acc[m][n], 0, 0, 0);
                acc[m][n] = __builtin_amdgcn_mfma_f32_16x16x32_bf16(
                    ah[m], bl[n], acc[m][n], 0, 0, 0);
                acc[m][n] = __builtin_amdgcn_mfma_f32_16x16x32_bf16(
                    al[m], bh[n], acc[m][n], 0, 0, 0);
            }
        __syncthreads();
    }

    // epilogue: C/D layout col=lane&15, row=(lane>>4)*4+reg
#pragma unroll
    for (int n = 0; n < FN; n++) {
        const int gc = colBase + wc * (BNt / 2) + n * 16 + lrow;
        const float bv = bias[gc];
#pragma unroll
        for (int m = 0; m < FM; m++) {
            const int gr0 = rowBase + wr * (BMt / 2) + m * 16 + (lane >> 4) * 4;
#pragma unroll
            for (int r = 0; r < 4; r++) {
                float v = acc[m][n][r] + bv;
                if (RELU) v = v > 0.f ? v : 0.f;
                Cout[(size_t)(gr0 + r) * N + gc] = v;
            }
        }
    }
}

// ---------------- fast tanh ----------------
__device__ __forceinline__ float tanh_fast(float x) {
    float ax = fminf(fabsf(x), 12.0f);
    float e  = __expf(2.0f * ax);
    float t  = 1.0f - __fdividef(2.0f, e + 1.0f);
    return copysignf(t, x);
}

// ---------------- Fused scores -> masked softmax -> agg. One WG per (b, p). --
// r10 structure + single-float4 pa/ww staging (tid<128 stages pa, tid>=128 ww).
__global__ __launch_bounds__(256) void attn_fused(
    const int* __restrict__ flag,
    const float* __restrict__ pa,          // [B*LP, H] (stash in d_out)
    const float* __restrict__ an,          // [B*LA, H] f32 (ws)
    const float* __restrict__ answer,      // [B*LA, DA]
    const int* __restrict__ amask,         // [B, LA]
    const float* __restrict__ ww,          // [H]
    const float* __restrict__ wbp,         // [1]
    float* __restrict__ agg_out)           // [B*LP, DA]
{
    if (*flag != 1) return;
    __shared__ __attribute__((aligned(16))) float s_pa[HH_];
    __shared__ __attribute__((aligned(16))) float s_ww[HH_];
    __shared__ float s_sc[LA_];
    __shared__ float s_at[LA_];

    const int bp_idx = blockIdx.x;
    const int b = bp_idx >> 9;
    const int tid = threadIdx.x;

    if (tid < 128) {
        *(float4*)&s_pa[tid * 4] =
            *(const float4*)&pa[(size_t)bp_idx * HH_ + tid * 4];
    } else {
        const int t = tid - 128;
        *(float4*)&s_ww[t * 4] = *(const float4*)&ww[t * 4];
    }
    __syncthreads();

    // scores: 32 a-values x 8 lanes; lane l covers h = i*32 + l*4 + {0..3}
    const int a = tid >> 3, l = tid & 7;
    const float* anr = an + (size_t)(b * LA_ + a) * HH_;
    float part = 0.f;
#pragma unroll
    for (int i = 0; i < HH_ / 32; i++) {
        const int h0 = i * 32 + l * 4;
        const float4 av = *(const float4*)&anr[h0];
        const float4 pv = *(const float4*)&s_pa[h0];
        const float4 wv = *(const float4*)&s_ww[h0];
        part += tanh_fast(pv.x + av.x) * wv.x;
        part += tanh_fast(pv.y + av.y) * wv.y;
        part += tanh_fast(pv.z + av.z) * wv.z;
        part += tanh_fast(pv.w + av.w) * wv.w;
    }
    part += __shfl_down(part, 4, 8);
    part += __shfl_down(part, 2, 8);
    part += __shfl_down(part, 1, 8);
    if (l == 0) {
        float sc = part + wbp[0];
        if (amask[b * LA_ + a] == 0) sc = -1e8f;
        s_sc[a] = sc;
    }
    __syncthreads();

    // softmax over LA_=32
    if (tid < 32) {
        float s = s_sc[tid];
        float m = s;
        for (int off = 16; off > 0; off >>= 1) m = fmaxf(m, __shfl_xor(m, off, 32));
        float e = __expf(s - m);
        float sum = e;
        for (int off = 16; off > 0; off >>= 1) sum += __shfl_xor(sum, off, 32);
        s_at[tid] = e / sum;
    }
    __syncthreads();

    // agg: thread handles d = tid*2, tid*2+1 (float2 coalesced)
    {
        const float* ansb = answer + (size_t)b * LA_ * DA_ + tid * 2;
        float ax = 0.f, ay = 0.f;
#pragma unroll
        for (int a2 = 0; a2 < LA_; a2++) {
            const float w = s_at[a2];
            const float2 v = *(const float2*)&ansb[(size_t)a2 * DA_];
            ax += w * v.x;
            ay += w * v.y;
        }
        float2 o; o.x = ax; o.y = ay;
        *(float2*)&agg_out[(size_t)bp_idx * DA_ + tid * 2] = o;
    }
}

extern "C" void kernel_launch(void* const* d_in, const int* in_sizes, int n_in,
                              void* d_out, int out_size, void* d_ws, size_t ws_size,
                              hipStream_t stream) {
    const int* amask = (const int*)d_in[3];

    const int M1 = B_ * LA_;   // 512
    const int M2 = B_ * LP_;   // 8192

    int* flag = (int*)d_ws;

    detect_mode<<<1, 1024, 0, stream>>>((const unsigned short*)d_in[0], flag);

    // MODE 1 (f32 storage) — live path (10 consecutive rounds confirmed).
    // ws: [flag 16B][an 1MB][WpTH 1MB][WpTL 1MB][WaTH .5][WaTL .5][WoTH 3MB]
    //     [WoTL 3MB]  = 10.03 MB  (< proven 17.8 MB)
    // pa f32 (16 MB) stashed in d_out's aligned region: dead until the final
    // GEMM overwrites it, after attn consumed pa.
    const float* ppl    = (const float*)d_in[0];
    const float* answer = (const float*)d_in[2];
    const float* Wp     = (const float*)d_in[4];
    const float* bp     = (const float*)d_in[5];
    const float* Wa     = (const float*)d_in[6];
    const float* ba     = (const float*)d_in[7];
    const float* ww     = (const float*)d_in[8];
    const float* wb     = (const float*)d_in[9];
    const float* Wo     = (const float*)d_in[10];
    const float* bo     = (const float*)d_in[11];
    float* aligned_out = (float*)d_out;
    float* agg_out     = aligned_out + (size_t)M2 * DP_;

    char* cur = (char*)d_ws + 16;
    float* an_ws = (float*)cur;        cur += (size_t)M1 * HH_ * 4;
    ushort_t* WpTH = (ushort_t*)cur;   cur += (size_t)HH_ * DP_ * 2;
    ushort_t* WpTL = (ushort_t*)cur;   cur += (size_t)HH_ * DP_ * 2;
    ushort_t* WaTH = (ushort_t*)cur;   cur += (size_t)HH_ * DA_ * 2;
    ushort_t* WaTL = (ushort_t*)cur;   cur += (size_t)HH_ * DA_ * 2;
    ushort_t* WoTH = (ushort_t*)cur;   cur += (size_t)DO_ * (DP_ + DA_) * 2;
    ushort_t* WoTL = (ushort_t*)cur;

    float* pa_stash = aligned_out;     // first 16 MB of aligned region

    transpose_split_all<<<2304, 256, 0, stream>>>(
        flag, Wa, WaTH, WaTL, Wp, WpTH, WpTL, Wo, WoTH, WoTL);

    // an = answer @ Wa + ba   (M=512, N=512, K=512)   grid 64
    gemm_mfma_split<64, 64, 0, 0><<<(M1 / 64) * (HH_ / 64), 256, 0, stream>>>(
        flag, answer, nullptr, WaTH, WaTL, ba, an_ws, HH_, DA_);
    // pa = ppl @ Wp + bp      (M=8192, N=512, K=1024) grid 256
    gemm_mfma_split<128, 128, 0, 0><<<(M2 / 128) * (HH_ / 128), 256, 0, stream>>>(
        flag, ppl, nullptr, WpTH, WpTL, bp, pa_stash, HH_, DP_);
    // attn: grid 8192
    attn_fused<<<M2, 256, 0, stream>>>(
        flag, pa_stash, an_ws, answer, amask, ww, wb, agg_out);
    // aligned = relu(concat(ppl, agg) @ Wo + bo)  (M=8192, N=1024, K=1536)
    // 128x128 / BK32 / grid 512
    gemm_mfma_split<128, 128, 1, 1><<<(M2 / 128) * (DO_ / 128), 256, 0, stream>>>(
        flag, ppl, agg_out, WoTH, WoTL, bo, aligned_out, DO_, DP_ + DA_);
}

// Round 12
// 344.980 us; speedup vs baseline: 1.0619x; 1.0619x over previous
//
#include <hip/hip_runtime.h>
#include <hip/hip_bf16.h>
#include <math.h>

// Problem constants
#define B_  16
#define LP_ 512
#define LA_ 32
#define DP_ 1024
#define DA_ 512
#define HH_ 512
#define DO_ 1024

typedef unsigned short ushort_t;
typedef __attribute__((ext_vector_type(8))) short bf16x8;
typedef __attribute__((ext_vector_type(4))) float f32x4;

__device__ __forceinline__ ushort_t f2bs(float x) {
    __hip_bfloat16 b = __float2bfloat16(x);
    return *(ushort_t*)&b;
}
__device__ __forceinline__ float bs2f(ushort_t u) {
    __hip_bfloat16 b = *(__hip_bfloat16*)&u;
    return __bfloat162float(b);
}

// LESSONS ENCODED (measured):
//  r8/r9: no trunc-hi bit-twiddle staging — RNE/RNE f2bs runs 112-113us @VGPR96;
//         trunc ran 146-155us @VGPR84 (compiler fuses f2bs pairs to cvt_pk).
//  r11:   global_load_lds B-staging neutral on GEMM (115 vs 113), negative in
//         attn staging split. Reverted — plain staging hides under barrier drain.
//  r12:   pa-GEMM was grid 256 = 1 blk/CU (no inter-block latency hiding, m114).
//         Fix: split-K (SPLITK template) — same 128x128 tile, grid 512, halves
//         write pa_part[0/1]; attn sums parts + adds bias.

// ---------------- dtype detector ----------------
// f32 storage -> low mantissa halves viewed as bf16 have huge random exponents.
// 11 passing rounds: flag==1 (f32). If flag==0 nothing runs -> loud fail.
__global__ void detect_mode(const unsigned short* __restrict__ raw,
                            int* __restrict__ flag) {
    __shared__ int cnt;
    if (threadIdx.x == 0) cnt = 0;
    __syncthreads();
    int e = (raw[threadIdx.x] >> 7) & 0xFF;
    if (e >= 160) atomicAdd(&cnt, 1);
    __syncthreads();
    if (threadIdx.x == 0) *flag = (cnt > 0) ? 1 : 0;
}

// ---------------- fused transpose-split for all 3 weights (1 launch) --------
// f32 src[R][C] -> bf16 hi/lo planes dst[C][R] (RNE hi + RNE residual lo).
// grid sections: Wa 256 | Wp 512 | Wo 1536   (total 2304 blocks)
__global__ __launch_bounds__(256) void transpose_split_all(
    const int* __restrict__ flag,
    const float* __restrict__ Wa, ushort_t* __restrict__ WaTH, ushort_t* __restrict__ WaTL,
    const float* __restrict__ Wp, ushort_t* __restrict__ WpTH, ushort_t* __restrict__ WpTL,
    const float* __restrict__ Wo, ushort_t* __restrict__ WoTH, ushort_t* __restrict__ WoTL)
{
    if (*flag != 1) return;
    __shared__ float tile[32][33];
    int bid = blockIdx.x;
    const float* src; ushort_t* dH; ushort_t* dL; int R, C;
    if (bid < 256)      { src = Wa; dH = WaTH; dL = WaTL; R = DA_;       C = HH_; }
    else if (bid < 768) { src = Wp; dH = WpTH; dL = WpTL; R = DP_;       C = HH_; bid -= 256; }
    else                { src = Wo; dH = WoTH; dL = WoTL; R = DP_ + DA_; C = DO_; bid -= 768; }
    const int nbx = C / 32;
    const int bx = bid % nbx;
    const int by = bid / nbx;
    const int tx = threadIdx.x % 32, ty = threadIdx.x / 32;  // 32x8
    const int c0 = bx * 32, r0 = by * 32;
#pragma unroll
    for (int i = ty; i < 32; i += 8)
        tile[i][tx] = src[(size_t)(r0 + i) * C + c0 + tx];
    __syncthreads();
#pragma unroll
    for (int i = ty; i < 32; i += 8) {
        float x = tile[tx][i];
        ushort_t h = f2bs(x);
        float lo = x - bs2f(h);
        dH[(size_t)(c0 + i) * R + r0 + tx] = h;
        dL[(size_t)(c0 + i) * R + r0 + tx] = f2bs(lo);
    }
}

// ---------------- Split-bf16 MFMA GEMM — r10-faithful + SPLITK -------------
// C_f32[M,N] = A_f32[M,K] @ B[K,N] + bias; B as transposed bf16 hi/lo planes
// BTH/BTL [N][Bld]. 3 MFMA per fragment pair: AhBh + AhBl + AlBh (AlBl
// dropped, ~2^-16 rel). A split in-staging via RNE f2bs pairs (compiler fuses
// to v_cvt_pk_bf16_f32). A/B fragments share the same (lane-group,slot)->k
// convention -> any HW k-permutation cancels. C/D: col=lane&15,
// row=(lane>>4)*4+reg [HW-verified m89].
// SPLITK=1: grid = 2*tiles; half = bid/(grid/2) computes K-columns
// [half*K,(half+1)*K) into Cout + half*M*N (partials summed by consumer).
// bias may be nullptr (bias deferred to consumer).
template<int BMt, int BNt, int CONCAT, int RELU, int SPLITK>
__global__ __launch_bounds__(256) void gemm_mfma_split(
    const int* __restrict__ flag,
    const float* __restrict__ A0,
    const float* __restrict__ A1,
    const ushort_t* __restrict__ BTH,
    const ushort_t* __restrict__ BTL,
    const float* __restrict__ bias,
    float* __restrict__ Cout,
    int N, int K, int Ald, int Bld)
{
    if (*flag != 1) return;
    constexpr int SA = 40;   // 80 B row stride: 16B-aligned b128 reads, banks spread
    __shared__ ushort_t AsH[BMt * SA];
    __shared__ ushort_t AsL[BMt * SA];
    __shared__ ushort_t BsH[BNt * SA];
    __shared__ ushort_t BsL[BNt * SA];
    const int tid = threadIdx.x;
    const int nbx = N / BNt;

    int lbid = blockIdx.x;
    if (SPLITK) {
        const int bhalf = gridDim.x >> 1;
        const int half = (blockIdx.x >= bhalf) ? 1 : 0;
        lbid = blockIdx.x - half * bhalf;
        const size_t kofs = (size_t)half * K;
        A0  += kofs;                      // column offset within row (Ald stride)
        BTH += kofs;
        BTL += kofs;
        const int Mrows = (bhalf / nbx) * BMt;
        Cout += (size_t)half * Mrows * N; // partial-sum buffer for this half
    }
    const int colBase = (lbid % nbx) * BNt;
    const int rowBase = (lbid / nbx) * BMt;
    const int wid = tid >> 6, lane = tid & 63;
    const int wr = wid >> 1, wc = wid & 1;          // 2x2 wave grid
    const int lrow = lane & 15;
    const int lk8 = (lane >> 4) * 8;
    constexpr int FM = (BMt / 2) / 16;
    constexpr int FN = (BNt / 2) / 16;

    f32x4 acc[FM][FN] = {};

    for (int k0 = 0; k0 < K; k0 += 32) {
        // ---- stage A [BMt][32] f32 -> split hi/lo LDS (RNE/RNE, r10 form) ----
#pragma unroll
        for (int c = 0; c < BMt / 32; c++) {
            const int s = tid + c * 256;       // BMt*8 float4 slots
            const int row = s >> 3, k4 = (s & 7) * 4;
            const int gk = k0 + k4;            // mult of 4; never straddles DP_
            const float* ap;
            if (CONCAT) {
                ap = (gk < DP_) ? A0 + (size_t)(rowBase + row) * DP_ + gk
                                : A1 + (size_t)(rowBase + row) * DA_ + (gk - DP_);
            } else {
                ap = A0 + (size_t)(rowBase + row) * Ald + gk;
            }
            const float4 v = *(const float4*)ap;
            const float xs[4] = {v.x, v.y, v.z, v.w};
            ushort_t h[4], l[4];
#pragma unroll
            for (int j = 0; j < 4; j++) {
                h[j] = f2bs(xs[j]);
                l[j] = f2bs(xs[j] - bs2f(h[j]));
            }
            *(uint2*)&AsH[row * SA + k4] = *(const uint2*)h;
            *(uint2*)&AsL[row * SA + k4] = *(const uint2*)l;
        }
        // ---- stage B [BNt][32] from bf16 planes (pure copies) ----
#pragma unroll
        for (int c = 0; c < BNt / 64; c++) {
            const int chunk = tid + c * 256;   // BNt*4 uint4 slots
            const int row = chunk >> 2, k8 = (chunk & 3) * 8;
            const size_t off = (size_t)(colBase + row) * Bld + k0 + k8;
            *(uint4*)&BsH[row * SA + k8] = *(const uint4*)(BTH + off);
            *(uint4*)&BsL[row * SA + k8] = *(const uint4*)(BTL + off);
        }
        __syncthreads();

        bf16x8 ah[FM], al[FM], bh[FN], bl[FN];
#pragma unroll
        for (int m = 0; m < FM; m++) {
            const int r = (wr * (BMt / 2) + m * 16 + lrow) * SA + lk8;
            ah[m] = *(const bf16x8*)&AsH[r];
            al[m] = *(const bf16x8*)&AsL[r];
        }
#pragma unroll
        for (int n = 0; n < FN; n++) {
            const int r = (wc * (BNt / 2) + n * 16 + lrow) * SA + lk8;
            bh[n] = *(const bf16x8*)&BsH[r];
            bl[n] = *(const bf16x8*)&BsL[r];
        }
#pragma unroll
        for (int m = 0; m < FM; m++)
#pragma unroll
            for (int n = 0; n < FN; n++) {
                acc[m][n] = __builtin_amdgcn_mfma_f32_16x16x32_bf16(
                    ah[m], bh[n], acc[m][n], 0, 0, 0);
                acc[m][n] = __builtin_amdgcn_mfma_f32_16x16x32_bf16(
                    ah[m], bl[n], acc[m][n], 0, 0, 0);
                acc[m][n] = __builtin_amdgcn_mfma_f32_16x16x32_bf16(
                    al[m], bh[n], acc[m][n], 0, 0, 0);
            }
        __syncthreads();
    }

    // epilogue: C/D layout col=lane&15, row=(lane>>4)*4+reg
#pragma unroll
    for (int n = 0; n < FN; n++) {
        const int gc = colBase + wc * (BNt / 2) + n * 16 + lrow;
        const float bv = bias ? bias[gc] : 0.f;
#pragma unroll
        for (int m = 0; m < FM; m++) {
            const int gr0 = rowBase + wr * (BMt / 2) + m * 16 + (lane >> 4) * 4;
#pragma unroll
            for (int r = 0; r < 4; r++) {
                float v = acc[m][n][r] + bv;
                if (RELU) v = v > 0.f ? v : 0.f;
                Cout[(size_t)(gr0 + r) * N + gc] = v;
            }
        }
    }
}

// ---------------- fast tanh ----------------
__device__ __forceinline__ float tanh_fast(float x) {
    float ax = fminf(fabsf(x), 12.0f);
    float e  = __expf(2.0f * ax);
    float t  = 1.0f - __fdividef(2.0f, e + 1.0f);
    return copysignf(t, x);
}

// ---------------- Fused scores -> masked softmax -> agg. One WG per (b, p). --
// r10 structure; pa arrives as two split-K partials (pa0+pa1) + deferred bias.
__global__ __launch_bounds__(256) void attn_fused(
    const int* __restrict__ flag,
    const float* __restrict__ pa0,         // [B*LP, H] partial (d_out stash)
    const float* __restrict__ pa1,         // [B*LP, H] partial
    const float* __restrict__ bpb,         // [H] deferred pa bias
    const float* __restrict__ an,          // [B*LA, H] f32 (ws)
    const float* __restrict__ answer,      // [B*LA, DA]
    const int* __restrict__ amask,         // [B, LA]
    const float* __restrict__ ww,          // [H]
    const float* __restrict__ wbp,         // [1]
    float* __restrict__ agg_out)           // [B*LP, DA]
{
    if (*flag != 1) return;
    __shared__ __attribute__((aligned(16))) float s_pa[HH_];
    __shared__ __attribute__((aligned(16))) float s_ww[HH_];
    __shared__ float s_sc[LA_];
    __shared__ float s_at[LA_];

    const int bp_idx = blockIdx.x;
    const int b = bp_idx >> 9;
    const int tid = threadIdx.x;

    for (int h = tid; h < HH_; h += 256) {
        const size_t idx = (size_t)bp_idx * HH_ + h;
        s_pa[h] = pa0[idx] + pa1[idx] + bpb[h];
        s_ww[h] = ww[h];
    }
    __syncthreads();

    // scores: 32 a-values x 8 lanes; lane l covers h = i*32 + l*4 + {0..3}
    const int a = tid >> 3, l = tid & 7;
    const float* anr = an + (size_t)(b * LA_ + a) * HH_;
    float part = 0.f;
#pragma unroll
    for (int i = 0; i < HH_ / 32; i++) {
        const int h0 = i * 32 + l * 4;
        const float4 av = *(const float4*)&anr[h0];
        const float4 pv = *(const float4*)&s_pa[h0];
        const float4 wv = *(const float4*)&s_ww[h0];
        part += tanh_fast(pv.x + av.x) * wv.x;
        part += tanh_fast(pv.y + av.y) * wv.y;
        part += tanh_fast(pv.z + av.z) * wv.z;
        part += tanh_fast(pv.w + av.w) * wv.w;
    }
    part += __shfl_down(part, 4, 8);
    part += __shfl_down(part, 2, 8);
    part += __shfl_down(part, 1, 8);
    if (l == 0) {
        float sc = part + wbp[0];
        if (amask[b * LA_ + a] == 0) sc = -1e8f;
        s_sc[a] = sc;
    }
    __syncthreads();

    // softmax over LA_=32
    if (tid < 32) {
        float s = s_sc[tid];
        float m = s;
        for (int off = 16; off > 0; off >>= 1) m = fmaxf(m, __shfl_xor(m, off, 32));
        float e = __expf(s - m);
        float sum = e;
        for (int off = 16; off > 0; off >>= 1) sum += __shfl_xor(sum, off, 32);
        s_at[tid] = e / sum;
    }
    __syncthreads();

    // agg: thread handles d = tid*2, tid*2+1 (float2 coalesced)
    {
        const float* ansb = answer + (size_t)b * LA_ * DA_ + tid * 2;
        float ax = 0.f, ay = 0.f;
#pragma unroll
        for (int a2 = 0; a2 < LA_; a2++) {
            const float w = s_at[a2];
            const float2 v = *(const float2*)&ansb[(size_t)a2 * DA_];
            ax += w * v.x;
            ay += w * v.y;
        }
        float2 o; o.x = ax; o.y = ay;
        *(float2*)&agg_out[(size_t)bp_idx * DA_ + tid * 2] = o;
    }
}

extern "C" void kernel_launch(void* const* d_in, const int* in_sizes, int n_in,
                              void* d_out, int out_size, void* d_ws, size_t ws_size,
                              hipStream_t stream) {
    const int* amask = (const int*)d_in[3];

    const int M1 = B_ * LA_;   // 512
    const int M2 = B_ * LP_;   // 8192

    int* flag = (int*)d_ws;

    detect_mode<<<1, 1024, 0, stream>>>((const unsigned short*)d_in[0], flag);

    // MODE 1 (f32 storage) — live path (11 consecutive rounds confirmed).
    // ws: [flag 16B][an 1MB][WpTH 1MB][WpTL 1MB][WaTH .5][WaTL .5][WoTH 3MB]
    //     [WoTL 3MB]  = 10.03 MB  (< proven 17.8 MB)
    // pa split-K partials pa0/pa1 (2 x 16 MB) fill d_out's aligned region
    // (32 MB) exactly; dead until the final GEMM overwrites it (after attn
    // consumed both partials). agg lives at aligned+32MB, untouched.
    const float* ppl    = (const float*)d_in[0];
    const float* answer = (const float*)d_in[2];
    const float* Wp     = (const float*)d_in[4];
    const float* bp     = (const float*)d_in[5];
    const float* Wa     = (const float*)d_in[6];
    const float* ba     = (const float*)d_in[7];
    const float* ww     = (const float*)d_in[8];
    const float* wb     = (const float*)d_in[9];
    const float* Wo     = (const float*)d_in[10];
    const float* bo     = (const float*)d_in[11];
    float* aligned_out = (float*)d_out;
    float* agg_out     = aligned_out + (size_t)M2 * DP_;

    char* cur = (char*)d_ws + 16;
    float* an_ws = (float*)cur;        cur += (size_t)M1 * HH_ * 4;
    ushort_t* WpTH = (ushort_t*)cur;   cur += (size_t)HH_ * DP_ * 2;
    ushort_t* WpTL = (ushort_t*)cur;   cur += (size_t)HH_ * DP_ * 2;
    ushort_t* WaTH = (ushort_t*)cur;   cur += (size_t)HH_ * DA_ * 2;
    ushort_t* WaTL = (ushort_t*)cur;   cur += (size_t)HH_ * DA_ * 2;
    ushort_t* WoTH = (ushort_t*)cur;   cur += (size_t)DO_ * (DP_ + DA_) * 2;
    ushort_t* WoTL = (ushort_t*)cur;

    float* pa0 = aligned_out;                       // [8192,512] partial, 16 MB
    float* pa1 = aligned_out + (size_t)M2 * HH_;    // second partial, 16 MB

    transpose_split_all<<<2304, 256, 0, stream>>>(
        flag, Wa, WaTH, WaTL, Wp, WpTH, WpTL, Wo, WoTH, WoTL);

    // an = answer @ Wa + ba   (M=512, N=512, K=512)   grid 64
    gemm_mfma_split<64, 64, 0, 0, 0><<<(M1 / 64) * (HH_ / 64), 256, 0, stream>>>(
        flag, answer, nullptr, WaTH, WaTL, ba, an_ws, HH_, DA_, DA_, DA_);
    // pa = ppl @ Wp (bias deferred)  (M=8192, N=512, K=1024) — SPLIT-K:
    // grid 512 = 2 halves x 256 tiles -> 2 blk/CU (was 1). K=512 per half.
    gemm_mfma_split<128, 128, 0, 0, 1><<<2 * (M2 / 128) * (HH_ / 128), 256, 0, stream>>>(
        flag, ppl, nullptr, WpTH, WpTL, nullptr, pa0, HH_, DP_ / 2, DP_, DP_);
    // attn: grid 8192; sums pa partials + bias in staging
    attn_fused<<<M2, 256, 0, stream>>>(
        flag, pa0, pa1, bp, an_ws, answer, amask, ww, wb, agg_out);
    // aligned = relu(concat(ppl, agg) @ Wo + bo)  (M=8192, N=1024, K=1536)
    // 128x128 / BK32 / grid 512 (measured best: 112-113us)
    gemm_mfma_split<128, 128, 1, 1, 0><<<(M2 / 128) * (DO_ / 128), 256, 0, stream>>>(
        flag, ppl, agg_out, WoTH, WoTL, bo, aligned_out,
        DO_, DP_ + DA_, DP_ + DA_, DP_ + DA_);
}

// Round 14
// 342.685 us; speedup vs baseline: 1.0690x; 1.0067x over previous
//
#include <hip/hip_runtime.h>
#include <hip/hip_bf16.h>
#include <math.h>

// Problem constants
#define B_  16
#define LP_ 512
#define LA_ 32
#define DP_ 1024
#define DA_ 512
#define HH_ 512
#define DO_ 1024

typedef unsigned short ushort_t;
typedef __attribute__((ext_vector_type(8))) short bf16x8;
typedef __attribute__((ext_vector_type(4))) float f32x4;

__device__ __forceinline__ ushort_t f2bs(float x) {
    __hip_bfloat16 b = __float2bfloat16(x);
    return *(ushort_t*)&b;
}
__device__ __forceinline__ float bs2f(ushort_t u) {
    __hip_bfloat16 b = *(__hip_bfloat16*)&u;
    return __bfloat162float(b);
}

// LESSONS ENCODED (measured):
//  r8/r9: no trunc-hi bit-twiddle staging — RNE/RNE f2bs runs 105-113us;
//         trunc ran 146-155us (compiler fuses f2bs pairs to cvt_pk).
//  r8:    no XCD swizzle (regressed final GEMM).
//  r11:   global_load_lds B-staging neutral; reverted.
//  r12:   pa split-K (1->2 blk/CU) won ~-10us (m114 wave-overlap). 345us, PASS.
//  r13:   FAILED replay-determinism (post-timing absmax 1.83) + slower (450us)
//         with {aux-fused an-GEMM, T14 reg-staged GEMM pipeline, attn hoist}
//         bundled. REVERTED (a)+(b) — race not localizable. Kept only the
//         provably race-free attn answer-load hoist (register-only).

// ---------------- dtype detector ----------------
// f32 storage -> low mantissa halves viewed as bf16 have huge random exponents.
// 12 passing rounds: flag==1 (f32). If flag==0 nothing runs -> loud fail.
__global__ void detect_mode(const unsigned short* __restrict__ raw,
                            int* __restrict__ flag) {
    __shared__ int cnt;
    if (threadIdx.x == 0) cnt = 0;
    __syncthreads();
    int e = (raw[threadIdx.x] >> 7) & 0xFF;
    if (e >= 160) atomicAdd(&cnt, 1);
    __syncthreads();
    if (threadIdx.x == 0) *flag = (cnt > 0) ? 1 : 0;
}

// ---------------- fused transpose-split for all 3 weights (1 launch) --------
// f32 src[R][C] -> bf16 hi/lo planes dst[C][R] (RNE hi + RNE residual lo).
// grid sections: Wa 256 | Wp 512 | Wo 1536   (total 2304 blocks)
__global__ __launch_bounds__(256) void transpose_split_all(
    const int* __restrict__ flag,
    const float* __restrict__ Wa, ushort_t* __restrict__ WaTH, ushort_t* __restrict__ WaTL,
    const float* __restrict__ Wp, ushort_t* __restrict__ WpTH, ushort_t* __restrict__ WpTL,
    const float* __restrict__ Wo, ushort_t* __restrict__ WoTH, ushort_t* __restrict__ WoTL)
{
    if (*flag != 1) return;
    __shared__ float tile[32][33];
    int bid = blockIdx.x;
    const float* src; ushort_t* dH; ushort_t* dL; int R, C;
    if (bid < 256)      { src = Wa; dH = WaTH; dL = WaTL; R = DA_;       C = HH_; }
    else if (bid < 768) { src = Wp; dH = WpTH; dL = WpTL; R = DP_;       C = HH_; bid -= 256; }
    else                { src = Wo; dH = WoTH; dL = WoTL; R = DP_ + DA_; C = DO_; bid -= 768; }
    const int nbx = C / 32;
    const int bx = bid % nbx;
    const int by = bid / nbx;
    const int tx = threadIdx.x % 32, ty = threadIdx.x / 32;  // 32x8
    const int c0 = bx * 32, r0 = by * 32;
#pragma unroll
    for (int i = ty; i < 32; i += 8)
        tile[i][tx] = src[(size_t)(r0 + i) * C + c0 + tx];
    __syncthreads();
#pragma unroll
    for (int i = ty; i < 32; i += 8) {
        float x = tile[tx][i];
        ushort_t h = f2bs(x);
        float lo = x - bs2f(h);
        dH[(size_t)(c0 + i) * R + r0 + tx] = h;
        dL[(size_t)(c0 + i) * R + r0 + tx] = f2bs(lo);
    }
}

// ---------------- Split-bf16 MFMA GEMM — r12-faithful + SPLITK -------------
// C_f32[M,N] = A_f32[M,K] @ B[K,N] + bias; B as transposed bf16 hi/lo planes
// BTH/BTL [N][Bld]. 3 MFMA per fragment pair: AhBh + AhBl + AlBh (AlBl
// dropped, ~2^-16 rel). A split in-staging via RNE f2bs pairs (compiler fuses
// to v_cvt_pk_bf16_f32). A/B fragments share the same (lane-group,slot)->k
// convention -> any HW k-permutation cancels. C/D: col=lane&15,
// row=(lane>>4)*4+reg [HW-verified m89].
// SPLITK=1: grid = 2*tiles; half = bid/(grid/2) computes K-columns
// [half*K,(half+1)*K) into Cout + half*M*N (partials summed by consumer).
// bias may be nullptr (bias deferred to consumer).
template<int BMt, int BNt, int CONCAT, int RELU, int SPLITK>
__global__ __launch_bounds__(256) void gemm_mfma_split(
    const int* __restrict__ flag,
    const float* __restrict__ A0,
    const float* __restrict__ A1,
    const ushort_t* __restrict__ BTH,
    const ushort_t* __restrict__ BTL,
    const float* __restrict__ bias,
    float* __restrict__ Cout,
    int N, int K, int Ald, int Bld)
{
    if (*flag != 1) return;
    constexpr int SA = 40;   // 80 B row stride: 16B-aligned b128 reads, banks spread
    __shared__ ushort_t AsH[BMt * SA];
    __shared__ ushort_t AsL[BMt * SA];
    __shared__ ushort_t BsH[BNt * SA];
    __shared__ ushort_t BsL[BNt * SA];
    const int tid = threadIdx.x;
    const int nbx = N / BNt;

    int lbid = blockIdx.x;
    if (SPLITK) {
        const int bhalf = gridDim.x >> 1;
        const int half = (blockIdx.x >= bhalf) ? 1 : 0;
        lbid = blockIdx.x - half * bhalf;
        const size_t kofs = (size_t)half * K;
        A0  += kofs;                      // column offset within row (Ald stride)
        BTH += kofs;
        BTL += kofs;
        const int Mrows = (bhalf / nbx) * BMt;
        Cout += (size_t)half * Mrows * N; // partial-sum buffer for this half
    }
    const int colBase = (lbid % nbx) * BNt;
    const int rowBase = (lbid / nbx) * BMt;
    const int wid = tid >> 6, lane = tid & 63;
    const int wr = wid >> 1, wc = wid & 1;          // 2x2 wave grid
    const int lrow = lane & 15;
    const int lk8 = (lane >> 4) * 8;
    constexpr int FM = (BMt / 2) / 16;
    constexpr int FN = (BNt / 2) / 16;

    f32x4 acc[FM][FN] = {};

    for (int k0 = 0; k0 < K; k0 += 32) {
        // ---- stage A [BMt][32] f32 -> split hi/lo LDS (RNE/RNE, r10 form) ----
#pragma unroll
        for (int c = 0; c < BMt / 32; c++) {
            const int s = tid + c * 256;       // BMt*8 float4 slots
            const int row = s >> 3, k4 = (s & 7) * 4;
            const int gk = k0 + k4;            // mult of 4; never straddles DP_
            const float* ap;
            if (CONCAT) {
                ap = (gk < DP_) ? A0 + (size_t)(rowBase + row) * DP_ + gk
                                : A1 + (size_t)(rowBase + row) * DA_ + (gk - DP_);
            } else {
                ap = A0 + (size_t)(rowBase + row) * Ald + gk;
            }
            const float4 v = *(const float4*)ap;
            const float xs[4] = {v.x, v.y, v.z, v.w};
            ushort_t h[4], l[4];
#pragma unroll
            for (int j = 0; j < 4; j++) {
                h[j] = f2bs(xs[j]);
                l[j] = f2bs(xs[j] - bs2f(h[j]));
            }
            *(uint2*)&AsH[row * SA + k4] = *(const uint2*)h;
            *(uint2*)&AsL[row * SA + k4] = *(const uint2*)l;
        }
        // ---- stage B [BNt][32] from bf16 planes (pure copies) ----
#pragma unroll
        for (int c = 0; c < BNt / 64; c++) {
            const int chunk = tid + c * 256;   // BNt*4 uint4 slots
            const int row = chunk >> 2, k8 = (chunk & 3) * 8;
            const size_t off = (size_t)(colBase + row) * Bld + k0 + k8;
            *(uint4*)&BsH[row * SA + k8] = *(const uint4*)(BTH + off);
            *(uint4*)&BsL[row * SA + k8] = *(const uint4*)(BTL + off);
        }
        __syncthreads();

        bf16x8 ah[FM], al[FM], bh[FN], bl[FN];
#pragma unroll
        for (int m = 0; m < FM; m++) {
            const int r = (wr * (BMt / 2) + m * 16 + lrow) * SA + lk8;
            ah[m] = *(const bf16x8*)&AsH[r];
            al[m] = *(const bf16x8*)&AsL[r];
        }
#pragma unroll
        for (int n = 0; n < FN; n++) {
            const int r = (wc * (BNt / 2) + n * 16 + lrow) * SA + lk8;
            bh[n] = *(const bf16x8*)&BsH[r];
            bl[n] = *(const bf16x8*)&BsL[r];
        }
#pragma unroll
        for (int m = 0; m < FM; m++)
#pragma unroll
            for (int n = 0; n < FN; n++) {
                acc[m][n] = __builtin_amdgcn_mfma_f32_16x16x32_bf16(
                    ah[m], bh[n], acc[m][n], 0, 0, 0);
                acc[m][n] = __builtin_amdgcn_mfma_f32_16x16x32_bf16(
                    ah[m], bl[n], acc[m][n], 0, 0, 0);
                acc[m][n] = __builtin_amdgcn_mfma_f32_16x16x32_bf16(
                    al[m], bh[n], acc[m][n], 0, 0, 0);
            }
        __syncthreads();
    }

    // epilogue: C/D layout col=lane&15, row=(lane>>4)*4+reg
#pragma unroll
    for (int n = 0; n < FN; n++) {
        const int gc = colBase + wc * (BNt / 2) + n * 16 + lrow;
        const float bv = bias ? bias[gc] : 0.f;
#pragma unroll
        for (int m = 0; m < FM; m++) {
            const int gr0 = rowBase + wr * (BMt / 2) + m * 16 + (lane >> 4) * 4;
#pragma unroll
            for (int r = 0; r < 4; r++) {
                float v = acc[m][n][r] + bv;
                if (RELU) v = v > 0.f ? v : 0.f;
                Cout[(size_t)(gr0 + r) * N + gc] = v;
            }
        }
    }
}

// ---------------- fast tanh ----------------
__device__ __forceinline__ float tanh_fast(float x) {
    float ax = fminf(fabsf(x), 12.0f);
    float e  = __expf(2.0f * ax);
    float t  = 1.0f - __fdividef(2.0f, e + 1.0f);
    return copysignf(t, x);
}

// ---------------- Fused scores -> masked softmax -> agg. One WG per (b, p). --
// pa arrives as two split-K partials (pa0+pa1) + deferred bias.
// Register-only hoist: answer loads are issued between the score barrier and
// the softmax (they don't depend on s_at) so their L2 latency hides under the
// 32-lane softmax phase. No shared-state change -> provably race-free.
__global__ __launch_bounds__(256) void attn_fused(
    const int* __restrict__ flag,
    const float* __restrict__ pa0,         // [B*LP, H] partial (d_out stash)
    const float* __restrict__ pa1,         // [B*LP, H] partial
    const float* __restrict__ bpb,         // [H] deferred pa bias
    const float* __restrict__ an,          // [B*LA, H] f32 (ws)
    const float* __restrict__ answer,      // [B*LA, DA]
    const int* __restrict__ amask,         // [B, LA]
    const float* __restrict__ ww,          // [H]
    const float* __restrict__ wbp,         // [1]
    float* __restrict__ agg_out)           // [B*LP, DA]
{
    if (*flag != 1) return;
    __shared__ __attribute__((aligned(16))) float s_pa[HH_];
    __shared__ __attribute__((aligned(16))) float s_ww[HH_];
    __shared__ float s_sc[LA_];
    __shared__ float s_at[LA_];

    const int bp_idx = blockIdx.x;
    const int b = bp_idx >> 9;
    const int tid = threadIdx.x;

    for (int h = tid; h < HH_; h += 256) {
        const size_t idx = (size_t)bp_idx * HH_ + h;
        s_pa[h] = pa0[idx] + pa1[idx] + bpb[h];
        s_ww[h] = ww[h];
    }
    __syncthreads();

    // scores: 32 a-values x 8 lanes; lane l covers h = i*32 + l*4 + {0..3}
    const int a = tid >> 3, l = tid & 7;
    const float* anr = an + (size_t)(b * LA_ + a) * HH_;
    float part = 0.f;
#pragma unroll
    for (int i = 0; i < HH_ / 32; i++) {
        const int h0 = i * 32 + l * 4;
        const float4 av = *(const float4*)&anr[h0];
        const float4 pv = *(const float4*)&s_pa[h0];
        const float4 wv = *(const float4*)&s_ww[h0];
        part += tanh_fast(pv.x + av.x) * wv.x;
        part += tanh_fast(pv.y + av.y) * wv.y;
        part += tanh_fast(pv.z + av.z) * wv.z;
        part += tanh_fast(pv.w + av.w) * wv.w;
    }
    part += __shfl_down(part, 4, 8);
    part += __shfl_down(part, 2, 8);
    part += __shfl_down(part, 1, 8);
    if (l == 0) {
        float sc = part + wbp[0];
        if (amask[b * LA_ + a] == 0) sc = -1e8f;
        s_sc[a] = sc;
    }
    __syncthreads();

    // hoisted answer loads (independent of softmax result)
    const float* ansb = answer + (size_t)b * LA_ * DA_ + tid * 2;
    float2 ansreg[LA_];
#pragma unroll
    for (int a2 = 0; a2 < LA_; a2++)
        ansreg[a2] = *(const float2*)&ansb[(size_t)a2 * DA_];

    // softmax over LA_=32 (lanes 0..31 of wave 0)
    if (tid < 32) {
        float s = s_sc[tid];
        float m = s;
        for (int off = 16; off > 0; off >>= 1) m = fmaxf(m, __shfl_xor(m, off, 32));
        float e = __expf(s - m);
        float sum = e;
        for (int off = 16; off > 0; off >>= 1) sum += __shfl_xor(sum, off, 32);
        s_at[tid] = e / sum;
    }
    __syncthreads();

    // agg: thread handles d = tid*2, tid*2+1 from prefetched registers
    {
        float ax = 0.f, ay = 0.f;
#pragma unroll
        for (int a2 = 0; a2 < LA_; a2++) {
            const float w = s_at[a2];
            ax += w * ansreg[a2].x;
            ay += w * ansreg[a2].y;
        }
        float2 o; o.x = ax; o.y = ay;
        *(float2*)&agg_out[(size_t)bp_idx * DA_ + tid * 2] = o;
    }
}

extern "C" void kernel_launch(void* const* d_in, const int* in_sizes, int n_in,
                              void* d_out, int out_size, void* d_ws, size_t ws_size,
                              hipStream_t stream) {
    const int* amask = (const int*)d_in[3];

    const int M1 = B_ * LA_;   // 512
    const int M2 = B_ * LP_;   // 8192

    int* flag = (int*)d_ws;

    detect_mode<<<1, 1024, 0, stream>>>((const unsigned short*)d_in[0], flag);

    // MODE 1 (f32 storage) — live path (12 passing rounds confirmed).
    // ws: [flag 16B][an 1MB][WpTH 1MB][WpTL 1MB][WaTH .5][WaTL .5][WoTH 3MB]
    //     [WoTL 3MB]  = 10.03 MB  (< proven 17.8 MB)
    // pa split-K partials pa0/pa1 (2 x 16 MB) fill d_out's aligned region
    // (32 MB); dead until the final GEMM overwrites it (after attn consumed
    // both partials). agg output lives at aligned+32MB, untouched until attn.
    const float* ppl    = (const float*)d_in[0];
    const float* answer = (const float*)d_in[2];
    const float* Wp     = (const float*)d_in[4];
    const float* bp     = (const float*)d_in[5];
    const float* Wa     = (const float*)d_in[6];
    const float* ba     = (const float*)d_in[7];
    const float* ww     = (const float*)d_in[8];
    const float* wb     = (const float*)d_in[9];
    const float* Wo     = (const float*)d_in[10];
    const float* bo     = (const float*)d_in[11];
    float* aligned_out = (float*)d_out;
    float* agg_out     = aligned_out + (size_t)M2 * DP_;

    char* cur = (char*)d_ws + 16;
    float* an_ws = (float*)cur;        cur += (size_t)M1 * HH_ * 4;
    ushort_t* WpTH = (ushort_t*)cur;   cur += (size_t)HH_ * DP_ * 2;
    ushort_t* WpTL = (ushort_t*)cur;   cur += (size_t)HH_ * DP_ * 2;
    ushort_t* WaTH = (ushort_t*)cur;   cur += (size_t)HH_ * DA_ * 2;
    ushort_t* WaTL = (ushort_t*)cur;   cur += (size_t)HH_ * DA_ * 2;
    ushort_t* WoTH = (ushort_t*)cur;   cur += (size_t)DO_ * (DP_ + DA_) * 2;
    ushort_t* WoTL = (ushort_t*)cur;

    float* pa0 = aligned_out;                       // [8192,512] partial, 16 MB
    float* pa1 = aligned_out + (size_t)M2 * HH_;    // second partial, 16 MB

    transpose_split_all<<<2304, 256, 0, stream>>>(
        flag, Wa, WaTH, WaTL, Wp, WpTH, WpTL, Wo, WoTH, WoTL);

    // an = answer @ Wa + ba   (M=512, N=512, K=512)   grid 64
    gemm_mfma_split<64, 64, 0, 0, 0><<<(M1 / 64) * (HH_ / 64), 256, 0, stream>>>(
        flag, answer, nullptr, WaTH, WaTL, ba, an_ws, HH_, DA_, DA_, DA_);
    // pa = ppl @ Wp (bias deferred)  (M=8192, N=512, K=1024) — SPLIT-K:
    // grid 512 = 2 halves x 256 tiles -> 2 blk/CU. K=512 per half.
    gemm_mfma_split<128, 128, 0, 0, 1><<<2 * (M2 / 128) * (HH_ / 128), 256, 0, stream>>>(
        flag, ppl, nullptr, WpTH, WpTL, nullptr, pa0, HH_, DP_ / 2, DP_, DP_);
    // attn: grid 8192; sums pa partials + bias in staging
    attn_fused<<<M2, 256, 0, stream>>>(
        flag, pa0, pa1, bp, an_ws, answer, amask, ww, wb, agg_out);
    // aligned = relu(concat(ppl, agg) @ Wo + bo)  (M=8192, N=1024, K=1536)
    // 128x128 / BK32 / grid 512 (measured best: 105us, r12)
    gemm_mfma_split<128, 128, 1, 1, 0><<<(M2 / 128) * (DO_ / 128), 256, 0, stream>>>(
        flag, ppl, agg_out, WoTH, WoTL, bo, aligned_out,
        DO_, DP_ + DA_, DP_ + DA_, DP_ + DA_);
}

// Round 15
// 311.864 us; speedup vs baseline: 1.1747x; 1.0988x over previous
//
#include <hip/hip_runtime.h>
#include <hip/hip_bf16.h>
#include <math.h>

// Problem constants
#define B_  16
#define LP_ 512
#define LA_ 32
#define DP_ 1024
#define DA_ 512
#define HH_ 512
#define DO_ 1024

typedef unsigned short ushort_t;
typedef __attribute__((ext_vector_type(8))) short bf16x8;
typedef __attribute__((ext_vector_type(4))) float f32x4;

__device__ __forceinline__ ushort_t f2bs(float x) {
    __hip_bfloat16 b = __float2bfloat16(x);
    return *(ushort_t*)&b;
}
__device__ __forceinline__ float bs2f(ushort_t u) {
    __hip_bfloat16 b = *(__hip_bfloat16*)&u;
    return __bfloat162float(b);
}

// LESSONS ENCODED (measured):
//  r8/r9: no trunc-hi bit-twiddle staging — RNE/RNE f2bs runs 105-113us;
//         trunc ran 146-155us (compiler fuses f2bs pairs to cvt_pk).
//  r8:    no XCD swizzle (regressed final GEMM).
//  r11:   global_load_lds B-staging neutral; half-and-half attn staging split
//         negative. Reverted.
//  r12:   pa split-K (1->2 blk/CU) won ~-10us (m114 wave-overlap).
//  r13:   FAILED replay-determinism with {aux-fuse, T14 reg-pipeline} bundled.
//         Reverted. r14 (=r12+attn hoist) PASSED 342.7us; VGPR=44 proves the
//         compiler sank the "hoisted" loads — hoist was a no-op.
//  r14:   profiler: attn_fused = 110us, VALUBusy 79%, conflicts 0 — VALU-
//         issue-bound. __fdividef w/o fast-math = full IEEE div (~10 slots).
//  r15:   minimal-slot tanh: exp2 + v_rcp + fma + free |x| modifier
//         (~13 slots/element vs ~22-25). GEMMs byte-identical to r14.

// ---------------- dtype detector ----------------
// f32 storage -> low mantissa halves viewed as bf16 have huge random exponents.
// 13 passing rounds: flag==1 (f32). If flag==0 nothing runs -> loud fail.
__global__ void detect_mode(const unsigned short* __restrict__ raw,
                            int* __restrict__ flag) {
    __shared__ int cnt;
    if (threadIdx.x == 0) cnt = 0;
    __syncthreads();
    int e = (raw[threadIdx.x] >> 7) & 0xFF;
    if (e >= 160) atomicAdd(&cnt, 1);
    __syncthreads();
    if (threadIdx.x == 0) *flag = (cnt > 0) ? 1 : 0;
}

// ---------------- fused transpose-split for all 3 weights (1 launch) --------
// f32 src[R][C] -> bf16 hi/lo planes dst[C][R] (RNE hi + RNE residual lo).
// grid sections: Wa 256 | Wp 512 | Wo 1536   (total 2304 blocks)
__global__ __launch_bounds__(256) void transpose_split_all(
    const int* __restrict__ flag,
    const float* __restrict__ Wa, ushort_t* __restrict__ WaTH, ushort_t* __restrict__ WaTL,
    const float* __restrict__ Wp, ushort_t* __restrict__ WpTH, ushort_t* __restrict__ WpTL,
    const float* __restrict__ Wo, ushort_t* __restrict__ WoTH, ushort_t* __restrict__ WoTL)
{
    if (*flag != 1) return;
    __shared__ float tile[32][33];
    int bid = blockIdx.x;
    const float* src; ushort_t* dH; ushort_t* dL; int R, C;
    if (bid < 256)      { src = Wa; dH = WaTH; dL = WaTL; R = DA_;       C = HH_; }
    else if (bid < 768) { src = Wp; dH = WpTH; dL = WpTL; R = DP_;       C = HH_; bid -= 256; }
    else                { src = Wo; dH = WoTH; dL = WoTL; R = DP_ + DA_; C = DO_; bid -= 768; }
    const int nbx = C / 32;
    const int bx = bid % nbx;
    const int by = bid / nbx;
    const int tx = threadIdx.x % 32, ty = threadIdx.x / 32;  // 32x8
    const int c0 = bx * 32, r0 = by * 32;
#pragma unroll
    for (int i = ty; i < 32; i += 8)
        tile[i][tx] = src[(size_t)(r0 + i) * C + c0 + tx];
    __syncthreads();
#pragma unroll
    for (int i = ty; i < 32; i += 8) {
        float x = tile[tx][i];
        ushort_t h = f2bs(x);
        float lo = x - bs2f(h);
        dH[(size_t)(c0 + i) * R + r0 + tx] = h;
        dL[(size_t)(c0 + i) * R + r0 + tx] = f2bs(lo);
    }
}

// ---------------- Split-bf16 MFMA GEMM — r12-faithful + SPLITK -------------
// C_f32[M,N] = A_f32[M,K] @ B[K,N] + bias; B as transposed bf16 hi/lo planes
// BTH/BTL [N][Bld]. 3 MFMA per fragment pair: AhBh + AhBl + AlBh (AlBl
// dropped, ~2^-16 rel). A split in-staging via RNE f2bs pairs (compiler fuses
// to v_cvt_pk_bf16_f32). A/B fragments share the same (lane-group,slot)->k
// convention -> any HW k-permutation cancels. C/D: col=lane&15,
// row=(lane>>4)*4+reg [HW-verified m89].
// SPLITK=1: grid = 2*tiles; half = bid/(grid/2) computes K-columns
// [half*K,(half+1)*K) into Cout + half*M*N (partials summed by consumer).
// bias may be nullptr (bias deferred to consumer).
template<int BMt, int BNt, int CONCAT, int RELU, int SPLITK>
__global__ __launch_bounds__(256) void gemm_mfma_split(
    const int* __restrict__ flag,
    const float* __restrict__ A0,
    const float* __restrict__ A1,
    const ushort_t* __restrict__ BTH,
    const ushort_t* __restrict__ BTL,
    const float* __restrict__ bias,
    float* __restrict__ Cout,
    int N, int K, int Ald, int Bld)
{
    if (*flag != 1) return;
    constexpr int SA = 40;   // 80 B row stride: 16B-aligned b128 reads, banks spread
    __shared__ ushort_t AsH[BMt * SA];
    __shared__ ushort_t AsL[BMt * SA];
    __shared__ ushort_t BsH[BNt * SA];
    __shared__ ushort_t BsL[BNt * SA];
    const int tid = threadIdx.x;
    const int nbx = N / BNt;

    int lbid = blockIdx.x;
    if (SPLITK) {
        const int bhalf = gridDim.x >> 1;
        const int half = (blockIdx.x >= bhalf) ? 1 : 0;
        lbid = blockIdx.x - half * bhalf;
        const size_t kofs = (size_t)half * K;
        A0  += kofs;                      // column offset within row (Ald stride)
        BTH += kofs;
        BTL += kofs;
        const int Mrows = (bhalf / nbx) * BMt;
        Cout += (size_t)half * Mrows * N; // partial-sum buffer for this half
    }
    const int colBase = (lbid % nbx) * BNt;
    const int rowBase = (lbid / nbx) * BMt;
    const int wid = tid >> 6, lane = tid & 63;
    const int wr = wid >> 1, wc = wid & 1;          // 2x2 wave grid
    const int lrow = lane & 15;
    const int lk8 = (lane >> 4) * 8;
    constexpr int FM = (BMt / 2) / 16;
    constexpr int FN = (BNt / 2) / 16;

    f32x4 acc[FM][FN] = {};

    for (int k0 = 0; k0 < K; k0 += 32) {
        // ---- stage A [BMt][32] f32 -> split hi/lo LDS (RNE/RNE, r10 form) ----
#pragma unroll
        for (int c = 0; c < BMt / 32; c++) {
            const int s = tid + c * 256;       // BMt*8 float4 slots
            const int row = s >> 3, k4 = (s & 7) * 4;
            const int gk = k0 + k4;            // mult of 4; never straddles DP_
            const float* ap;
            if (CONCAT) {
                ap = (gk < DP_) ? A0 + (size_t)(rowBase + row) * DP_ + gk
                                : A1 + (size_t)(rowBase + row) * DA_ + (gk - DP_);
            } else {
                ap = A0 + (size_t)(rowBase + row) * Ald + gk;
            }
            const float4 v = *(const float4*)ap;
            const float xs[4] = {v.x, v.y, v.z, v.w};
            ushort_t h[4], l[4];
#pragma unroll
            for (int j = 0; j < 4; j++) {
                h[j] = f2bs(xs[j]);
                l[j] = f2bs(xs[j] - bs2f(h[j]));
            }
            *(uint2*)&AsH[row * SA + k4] = *(const uint2*)h;
            *(uint2*)&AsL[row * SA + k4] = *(const uint2*)l;
        }
        // ---- stage B [BNt][32] from bf16 planes (pure copies) ----
#pragma unroll
        for (int c = 0; c < BNt / 64; c++) {
            const int chunk = tid + c * 256;   // BNt*4 uint4 slots
            const int row = chunk >> 2, k8 = (chunk & 3) * 8;
            const size_t off = (size_t)(colBase + row) * Bld + k0 + k8;
            *(uint4*)&BsH[row * SA + k8] = *(const uint4*)(BTH + off);
            *(uint4*)&BsL[row * SA + k8] = *(const uint4*)(BTL + off);
        }
        __syncthreads();

        bf16x8 ah[FM], al[FM], bh[FN], bl[FN];
#pragma unroll
        for (int m = 0; m < FM; m++) {
            const int r = (wr * (BMt / 2) + m * 16 + lrow) * SA + lk8;
            ah[m] = *(const bf16x8*)&AsH[r];
            al[m] = *(const bf16x8*)&AsL[r];
        }
#pragma unroll
        for (int n = 0; n < FN; n++) {
            const int r = (wc * (BNt / 2) + n * 16 + lrow) * SA + lk8;
            bh[n] = *(const bf16x8*)&BsH[r];
            bl[n] = *(const bf16x8*)&BsL[r];
        }
#pragma unroll
        for (int m = 0; m < FM; m++)
#pragma unroll
            for (int n = 0; n < FN; n++) {
                acc[m][n] = __builtin_amdgcn_mfma_f32_16x16x32_bf16(
                    ah[m], bh[n], acc[m][n], 0, 0, 0);
                acc[m][n] = __builtin_amdgcn_mfma_f32_16x16x32_bf16(
                    ah[m], bl[n], acc[m][n], 0, 0, 0);
                acc[m][n] = __builtin_amdgcn_mfma_f32_16x16x32_bf16(
                    al[m], bh[n], acc[m][n], 0, 0, 0);
            }
        __syncthreads();
    }

    // epilogue: C/D layout col=lane&15, row=(lane>>4)*4+reg
#pragma unroll
    for (int n = 0; n < FN; n++) {
        const int gc = colBase + wc * (BNt / 2) + n * 16 + lrow;
        const float bv = bias ? bias[gc] : 0.f;
#pragma unroll
        for (int m = 0; m < FM; m++) {
            const int gr0 = rowBase + wr * (BMt / 2) + m * 16 + (lane >> 4) * 4;
#pragma unroll
            for (int r = 0; r < 4; r++) {
                float v = acc[m][n][r] + bv;
                if (RELU) v = v > 0.f ? v : 0.f;
                Cout[(size_t)(gr0 + r) * N + gc] = v;
            }
        }
    }
}

// ---------------- minimal-slot tanh ----------------
// tanh(x) = copysign(1 - 2/(2^(|x|*2*log2 e) + 1), x).
// Slots: v_mul(|x| free modifier) + v_min + v_exp(4) + v_add + v_rcp(4)
//        + v_fma + v_bfi  ~= 13/element (was ~22-25: __fdividef w/o fast-math
//        emits the full IEEE div sequence).
__device__ __forceinline__ float tanh_fast(float x) {
    float t = fminf(fabsf(x) * 2.885390082f, 36.0f);  // 2*log2(e); clamp -> tanh=1
    float e = __builtin_amdgcn_exp2f(t);
    float r = __builtin_amdgcn_rcpf(e + 1.0f);
    float th = fmaf(-2.0f, r, 1.0f);
    return copysignf(th, x);
}

// ---------------- Fused scores -> masked softmax -> agg. One WG per (b, p). --
// pa arrives as two split-K partials (pa0+pa1) + deferred bias.
__global__ __launch_bounds__(256) void attn_fused(
    const int* __restrict__ flag,
    const float* __restrict__ pa0,         // [B*LP, H] partial (d_out stash)
    const float* __restrict__ pa1,         // [B*LP, H] partial
    const float* __restrict__ bpb,         // [H] deferred pa bias
    const float* __restrict__ an,          // [B*LA, H] f32 (ws)
    const float* __restrict__ answer,      // [B*LA, DA]
    const int* __restrict__ amask,         // [B, LA]
    const float* __restrict__ ww,          // [H]
    const float* __restrict__ wbp,         // [1]
    float* __restrict__ agg_out)           // [B*LP, DA]
{
    if (*flag != 1) return;
    __shared__ __attribute__((aligned(16))) float s_pa[HH_];
    __shared__ __attribute__((aligned(16))) float s_ww[HH_];
    __shared__ float s_sc[LA_];
    __shared__ float s_at[LA_];

    const int bp_idx = blockIdx.x;
    const int b = bp_idx >> 9;
    const int tid = threadIdx.x;

    for (int h = tid; h < HH_; h += 256) {
        const size_t idx = (size_t)bp_idx * HH_ + h;
        s_pa[h] = pa0[idx] + pa1[idx] + bpb[h];
        s_ww[h] = ww[h];
    }
    __syncthreads();

    // scores: 32 a-values x 8 lanes; lane l covers h = i*32 + l*4 + {0..3}
    const int a = tid >> 3, l = tid & 7;
    const float* anr = an + (size_t)(b * LA_ + a) * HH_;
    float part = 0.f;
#pragma unroll
    for (int i = 0; i < HH_ / 32; i++) {
        const int h0 = i * 32 + l * 4;
        const float4 av = *(const float4*)&anr[h0];
        const float4 pv = *(const float4*)&s_pa[h0];
        const float4 wv = *(const float4*)&s_ww[h0];
        part += tanh_fast(pv.x + av.x) * wv.x;
        part += tanh_fast(pv.y + av.y) * wv.y;
        part += tanh_fast(pv.z + av.z) * wv.z;
        part += tanh_fast(pv.w + av.w) * wv.w;
    }
    part += __shfl_down(part, 4, 8);
    part += __shfl_down(part, 2, 8);
    part += __shfl_down(part, 1, 8);
    if (l == 0) {
        float sc = part + wbp[0];
        if (amask[b * LA_ + a] == 0) sc = -1e8f;
        s_sc[a] = sc;
    }
    __syncthreads();

    // softmax over LA_=32 (lanes 0..31 of wave 0)
    if (tid < 32) {
        float s = s_sc[tid];
        float m = s;
        for (int off = 16; off > 0; off >>= 1) m = fmaxf(m, __shfl_xor(m, off, 32));
        float e = __expf(s - m);
        float sum = e;
        for (int off = 16; off > 0; off >>= 1) sum += __shfl_xor(sum, off, 32);
        s_at[tid] = e * __builtin_amdgcn_rcpf(sum);
    }
    __syncthreads();

    // agg: thread handles d = tid*2, tid*2+1 (float2 coalesced)
    {
        const float* ansb = answer + (size_t)b * LA_ * DA_ + tid * 2;
        float ax = 0.f, ay = 0.f;
#pragma unroll
        for (int a2 = 0; a2 < LA_; a2++) {
            const float w = s_at[a2];
            const float2 v = *(const float2*)&ansb[(size_t)a2 * DA_];
            ax += w * v.x;
            ay += w * v.y;
        }
        float2 o; o.x = ax; o.y = ay;
        *(float2*)&agg_out[(size_t)bp_idx * DA_ + tid * 2] = o;
    }
}

extern "C" void kernel_launch(void* const* d_in, const int* in_sizes, int n_in,
                              void* d_out, int out_size, void* d_ws, size_t ws_size,
                              hipStream_t stream) {
    const int* amask = (const int*)d_in[3];

    const int M1 = B_ * LA_;   // 512
    const int M2 = B_ * LP_;   // 8192

    int* flag = (int*)d_ws;

    detect_mode<<<1, 1024, 0, stream>>>((const unsigned short*)d_in[0], flag);

    // MODE 1 (f32 storage) — live path (13 passing rounds confirmed).
    // ws: [flag 16B][an 1MB][WpTH 1MB][WpTL 1MB][WaTH .5][WaTL .5][WoTH 3MB]
    //     [WoTL 3MB]  = 10.03 MB  (< proven 17.8 MB)
    // pa split-K partials pa0/pa1 (2 x 16 MB) fill d_out's aligned region
    // (32 MB); dead until the final GEMM overwrites it (after attn consumed
    // both partials). agg output lives at aligned+32MB, untouched until attn.
    const float* ppl    = (const float*)d_in[0];
    const float* answer = (const float*)d_in[2];
    const float* Wp     = (const float*)d_in[4];
    const float* bp     = (const float*)d_in[5];
    const float* Wa     = (const float*)d_in[6];
    const float* ba     = (const float*)d_in[7];
    const float* ww     = (const float*)d_in[8];
    const float* wb     = (const float*)d_in[9];
    const float* Wo     = (const float*)d_in[10];
    const float* bo     = (const float*)d_in[11];
    float* aligned_out = (float*)d_out;
    float* agg_out     = aligned_out + (size_t)M2 * DP_;

    char* cur = (char*)d_ws + 16;
    float* an_ws = (float*)cur;        cur += (size_t)M1 * HH_ * 4;
    ushort_t* WpTH = (ushort_t*)cur;   cur += (size_t)HH_ * DP_ * 2;
    ushort_t* WpTL = (ushort_t*)cur;   cur += (size_t)HH_ * DP_ * 2;
    ushort_t* WaTH = (ushort_t*)cur;   cur += (size_t)HH_ * DA_ * 2;
    ushort_t* WaTL = (ushort_t*)cur;   cur += (size_t)HH_ * DA_ * 2;
    ushort_t* WoTH = (ushort_t*)cur;   cur += (size_t)DO_ * (DP_ + DA_) * 2;
    ushort_t* WoTL = (ushort_t*)cur;

    float* pa0 = aligned_out;                       // [8192,512] partial, 16 MB
    float* pa1 = aligned_out + (size_t)M2 * HH_;    // second partial, 16 MB

    transpose_split_all<<<2304, 256, 0, stream>>>(
        flag, Wa, WaTH, WaTL, Wp, WpTH, WpTL, Wo, WoTH, WoTL);

    // an = answer @ Wa + ba   (M=512, N=512, K=512)   grid 64
    gemm_mfma_split<64, 64, 0, 0, 0><<<(M1 / 64) * (HH_ / 64), 256, 0, stream>>>(
        flag, answer, nullptr, WaTH, WaTL, ba, an_ws, HH_, DA_, DA_, DA_);
    // pa = ppl @ Wp (bias deferred)  (M=8192, N=512, K=1024) — SPLIT-K:
    // grid 512 = 2 halves x 256 tiles -> 2 blk/CU. K=512 per half.
    gemm_mfma_split<128, 128, 0, 0, 1><<<2 * (M2 / 128) * (HH_ / 128), 256, 0, stream>>>(
        flag, ppl, nullptr, WpTH, WpTL, nullptr, pa0, HH_, DP_ / 2, DP_, DP_);
    // attn: grid 8192; sums pa partials + bias in staging
    attn_fused<<<M2, 256, 0, stream>>>(
        flag, pa0, pa1, bp, an_ws, answer, amask, ww, wb, agg_out);
    // aligned = relu(concat(ppl, agg) @ Wo + bo)  (M=8192, N=1024, K=1536)
    // 128x128 / BK32 / grid 512 (measured best: 105us, r12)
    gemm_mfma_split<128, 128, 1, 1, 0><<<(M2 / 128) * (DO_ / 128), 256, 0, stream>>>(
        flag, ppl, agg_out, WoTH, WoTL, bo, aligned_out,
        DO_, DP_ + DA_, DP_ + DA_, DP_ + DA_);
}